// Round 2
// baseline (110.713 us; speedup 1.0000x reference)
//
#include <hip/hip_runtime.h>

// DropStripes (SpecAugment along time axis, dim=2).
// x: [B=64, C=1, T=4096, F=256] fp32; bgn, distance: [B, 2] int32.
// out = x * keep[b,t], keep = NOT any stripe covers t: t in [bgn, bgn+dist).
//
// Pure streaming masked copy, memory-bound (536.9 MB total traffic).
// R1: 4-deep ILP unroll (4 independent loads in flight per wave) +
//     non-temporal load/store hints (read-once/write-once streams).

typedef float v4f __attribute__((ext_vector_type(4)));

constexpr int T_DIM = 4096;          // time axis length
constexpr int F4 = 64;               // float4 per row (256 floats / 4)
constexpr int ROW_SHIFT = 6;         // log2(F4)

__device__ __forceinline__ v4f load_masked(const v4f* __restrict__ x,
                                           const int* __restrict__ bgn,
                                           const int* __restrict__ dist,
                                           int i) {
  const int t = (i >> ROW_SHIFT) & (T_DIM - 1);
  const int b = i >> (ROW_SHIFT + 12);   // 12 = log2(T_DIM)
  const int b0 = bgn[b * 2 + 0], b1 = bgn[b * 2 + 1];
  const int d0 = dist[b * 2 + 0], d1 = dist[b * 2 + 1];
  const bool drop = (t >= b0 && t < b0 + d0) || (t >= b1 && t < b1 + d1);
  v4f v = {0.f, 0.f, 0.f, 0.f};
  if (!drop) {                           // wave-uniform (wave == one t-row)
    v = __builtin_nontemporal_load(&x[i]);
  }
  return v;
}

__global__ __launch_bounds__(256) void drop_stripes_kernel(
    const v4f* __restrict__ x,
    const int* __restrict__ bgn,
    const int* __restrict__ dist,
    v4f*       __restrict__ out,
    int n4) {
  const int tid = blockIdx.x * blockDim.x + threadIdx.x;
  const int s = gridDim.x * blockDim.x;
  int i = tid;
  // Main unrolled loop: 4 independent load->store chains in flight.
  // For the fixed problem (n4 = 8 * 4*s) this covers everything with no tail.
  for (; i + 3 * s < n4; i += 4 * s) {
    v4f v0 = load_masked(x, bgn, dist, i);
    v4f v1 = load_masked(x, bgn, dist, i + s);
    v4f v2 = load_masked(x, bgn, dist, i + 2 * s);
    v4f v3 = load_masked(x, bgn, dist, i + 3 * s);
    __builtin_nontemporal_store(v0, &out[i]);
    __builtin_nontemporal_store(v1, &out[i + s]);
    __builtin_nontemporal_store(v2, &out[i + 2 * s]);
    __builtin_nontemporal_store(v3, &out[i + 3 * s]);
  }
  // Tail (not taken for the fixed shape; kept for robustness).
  for (; i < n4; i += s) {
    v4f v = load_masked(x, bgn, dist, i);
    __builtin_nontemporal_store(v, &out[i]);
  }
}

extern "C" void kernel_launch(void* const* d_in, const int* in_sizes, int n_in,
                              void* d_out, int out_size, void* d_ws, size_t ws_size,
                              hipStream_t stream) {
  const v4f* x    = (const v4f*)d_in[0];
  const int* bgn  = (const int*)d_in[1];
  const int* dist = (const int*)d_in[2];
  v4f* out        = (v4f*)d_out;

  const int n4 = out_size / 4;        // 16,777,216 float4s
  const int block = 256;
  const int grid = 2048;              // 524,288 threads; 8 unrolled iters each
  drop_stripes_kernel<<<grid, block, 0, stream>>>(x, bgn, dist, out, n4);
}

// Round 3
// 93.963 us; speedup vs baseline: 1.1783x; 1.1783x over previous
//
#include <hip/hip_runtime.h>

// DropStripes (SpecAugment along time axis, dim=2).
// x: [B=64, C=1, T=4096, F=256] fp32; bgn, distance: [B, 2] int32.
// out = x * keep[b,t], keep = NOT any stripe covers t: t in [bgn, bgn+dist).
//
// Memory-bound masked copy (536.9 MB traffic). R2: flat one-shot mapping —
// one float4 per thread, no grid-stride loop (R1's unroll+nontemporal
// regressed; 2048-block loop version was 5.07 TB/s vs 6.29 TB/s copy ceiling).

typedef float v4f __attribute__((ext_vector_type(4)));

constexpr int T_DIM = 4096;          // time axis length
constexpr int ROW_SHIFT = 6;         // log2(64 float4 per row)
constexpr int T_SHIFT = 12;          // log2(T_DIM)

__global__ __launch_bounds__(256) void drop_stripes_kernel(
    const v4f* __restrict__ x,
    const int* __restrict__ bgn,
    const int* __restrict__ dist,
    v4f*       __restrict__ out) {
  const int i = blockIdx.x * 256 + threadIdx.x;   // one float4 per thread
  const int row = i >> ROW_SHIFT;                 // global t-row index
  const int t = row & (T_DIM - 1);
  const int b = row >> T_SHIFT;

  // Per-sample stripe table: 2 stripes, 4 ints — L1/L2 resident, and b is
  // wave-uniform (one wave == one t-row), so the branch is non-divergent.
  const int b0 = bgn[b * 2 + 0], b1 = bgn[b * 2 + 1];
  const int d0 = dist[b * 2 + 0], d1 = dist[b * 2 + 1];
  const bool drop = (t >= b0 && t < b0 + d0) || (t >= b1 && t < b1 + d1);

  v4f v = {0.f, 0.f, 0.f, 0.f};
  if (!drop) {
    v = x[i];
  }
  out[i] = v;
}

extern "C" void kernel_launch(void* const* d_in, const int* in_sizes, int n_in,
                              void* d_out, int out_size, void* d_ws, size_t ws_size,
                              hipStream_t stream) {
  const v4f* x    = (const v4f*)d_in[0];
  const int* bgn  = (const int*)d_in[1];
  const int* dist = (const int*)d_in[2];
  v4f* out        = (v4f*)d_out;

  const int n4 = out_size / 4;        // 16,777,216 float4s (fixed shape)
  const int block = 256;
  const int grid = n4 / block;        // 65,536 blocks, exact cover, no tail
  drop_stripes_kernel<<<grid, block, 0, stream>>>(x, bgn, dist, out);
}